// Round 10
// baseline (2633.688 us; speedup 1.0000x reference)
//
#include <hip/hip_runtime.h>
#include <stdint.h>

#define NB 512    // batch
#define NT 32     // time steps
#define NIN 8     // input feats
#define NIN1 9    // + y_prev
#define NH 64     // hidden
#define NP 256    // particles
#define NTHR 1024 // 16 waves: wq = wv&7 (gate rows), mh = wv>>3 (particle half)
#define HROW 68   // f16 row stride: 136 B = 34 dwords -> 2-way bank alias (free)
#define WVR 74    // Wv_s row stride (73 used)

typedef __attribute__((ext_vector_type(8))) _Float16 f16x8;
typedef __attribute__((ext_vector_type(16))) float f32x16;

struct FKeys { uint32_t a[NT]; uint32_t b[NT]; };

// ---------------- Threefry-2x32-20 (exact JAX semantics) ----------------
__host__ __device__ __forceinline__ void tfr(uint32_t& x0, uint32_t& x1, int r) {
  x0 += x1; x1 = (x1 << r) | (x1 >> (32 - r)); x1 ^= x0;
}

__host__ __device__ __forceinline__ void threefry2x32(uint32_t k0, uint32_t k1,
                                                      uint32_t& x0, uint32_t& x1) {
  uint32_t k2 = k0 ^ k1 ^ 0x1BD11BDAu;
  x0 += k0; x1 += k1;
  tfr(x0,x1,13); tfr(x0,x1,15); tfr(x0,x1,26); tfr(x0,x1,6);
  x0 += k1; x1 += k2 + 1u;
  tfr(x0,x1,17); tfr(x0,x1,29); tfr(x0,x1,16); tfr(x0,x1,24);
  x0 += k2; x1 += k0 + 2u;
  tfr(x0,x1,13); tfr(x0,x1,15); tfr(x0,x1,26); tfr(x0,x1,6);
  x0 += k0; x1 += k1 + 3u;
  tfr(x0,x1,17); tfr(x0,x1,29); tfr(x0,x1,16); tfr(x0,x1,24);
  x0 += k1; x1 += k2 + 4u;
  tfr(x0,x1,13); tfr(x0,x1,15); tfr(x0,x1,26); tfr(x0,x1,6);
  x0 += k2; x1 += k0 + 5u;
}

// bits -> uniform -> sqrt(2)*erfinv  (XLA f32 path) — keep EXACT
__device__ __forceinline__ float normal_from_bits(uint32_t bits) {
  float f = __uint_as_float((bits >> 9) | 0x3f800000u) - 1.0f;
  const float lo = -0.99999994f;
  float u = fmaxf(lo, fmaf(f, 2.0f, lo));
  float w = -log1pf(-u * u);
  float p;
  if (w < 5.0f) {
    w -= 2.5f;
    p = 2.81022636e-08f;
    p = fmaf(p, w, 3.43273939e-07f);
    p = fmaf(p, w, -3.5233877e-06f);
    p = fmaf(p, w, -4.39150654e-06f);
    p = fmaf(p, w, 0.00021858087f);
    p = fmaf(p, w, -0.00125372503f);
    p = fmaf(p, w, -0.00417768164f);
    p = fmaf(p, w, 0.246640727f);
    p = fmaf(p, w, 1.50140941f);
  } else {
    w = sqrtf(w) - 3.0f;
    p = -0.000200214257f;
    p = fmaf(p, w, 0.000100950558f);
    p = fmaf(p, w, 0.00134934322f);
    p = fmaf(p, w, -0.00367342844f);
    p = fmaf(p, w, 0.00573950773f);
    p = fmaf(p, w, -0.0076224613f);
    p = fmaf(p, w, 0.00943887047f);
    p = fmaf(p, w, 1.00167406f);
    p = fmaf(p, w, 2.83297682f);
  }
  return 1.41421356f * (p * u);
}

__device__ __forceinline__ float frcp(float x) { return __builtin_amdgcn_rcpf(x); }
__device__ __forceinline__ float fsigmoid(float x) { return frcp(1.0f + __expf(-x)); }
__device__ __forceinline__ float ftanh(float x) { return 1.0f - 2.0f * frcp(1.0f + __expf(2.0f * x)); }

// f32 -> packed (f16 hi | f16 residual) : h = h1 + h2 with ~22-bit combined mantissa
__device__ __forceinline__ uint32_t pack_split(float x) {
  _Float16 a = (_Float16)x;
  _Float16 r = (_Float16)(x - (float)a);
  union { _Float16 h; uint16_t u; } ua, ur;
  ua.h = a; ur.h = r;
  return (uint32_t)ua.u | ((uint32_t)ur.u << 16);
}

// 8B-aligned LDS f16x8 load (two ds_read_b64, 2-way alias at HROW=68)
__device__ __forceinline__ f16x8 ld8h(const _Float16* p) {
  union { f16x8 v; uint64_t q[2]; } u;
  u.q[0] = *(const uint64_t*)(p);
  u.q[1] = *(const uint64_t*)(p + 4);
  return u.v;
}

// ---------------- main kernel: one block (1024 thr) per batch elem ----------------
// Gates GEMM per step: D[r'][p] = sum_j W'[r'][j] h[p][j], r' = 4k+gate.
// A = W' (2-way f16 split in registers, loaded once); B = h (f16 splits in LDS,
// physical rows == sorted slots; reads sequential -> conflict-free).
// Wave (wq,mh): lane (ln31,h5) owns cells (p = (2mh+mi)*32+ln31 [+128], k = 8wq+2q+h5),
// mi = 0..1 -> 16 cells/thread. xg / Wv / xs / lp-x are precomputed into LDS at init.
__global__ __launch_bounds__(NTHR, 1)
void pf_main(const float* __restrict__ input_data, const float* __restrict__ y_prev,
             const float* __restrict__ Wv, const float* __restrict__ bv,
             const float* __restrict__ W_ih, const float* __restrict__ W_hh,
             const float* __restrict__ b_ih, const float* __restrict__ b_hh,
             const float* __restrict__ Wp, const float* __restrict__ bp,
             const float* __restrict__ Wf, const float* __restrict__ bf,
             float* __restrict__ out, float* __restrict__ gw,
             FKeys fk)
{
  __shared__ __align__(16) _Float16 h1_s[NP * HROW];   // 34.8 KB
  __shared__ __align__(16) _Float16 h2_s[NP * HROW];   // 34.8 KB
  __shared__ __align__(16) float xg_all[NT * NP];      // 32 KB  [t][r']
  __shared__ __align__(16) float Wv_s[NH * WVR];       // 18.9 KB
  __shared__ __align__(16) float xs_all[NT][16];       // 2 KB
  __shared__ __align__(16) float proj_s[NP];
  __shared__ float lp_s[NP];
  __shared__ float wsum_s[NP];
  __shared__ int   rankP_s[4][NP];                     // 4 KB
  __shared__ float hsum2_s[2][NH];
  __shared__ float std_s[NH];
  __shared__ float lpx_s[NT];
  __shared__ float bv_s[NH];

  const int tid  = threadIdx.x;
  const int b    = blockIdx.x;
  const int lane = tid & 63;
  const int wv   = tid >> 6;          // 0..15
  const int wq   = wv & 7;            // gate-row group
  const int mh   = wv >> 3;           // particle half
  const int ln31 = lane & 31;
  const int h5   = lane >> 5;

  const float bf0 = bf[0];
  const float bp0 = bp[0];
  const uint32_t bsh = (uint32_t)b << 6;

  // ---- one-time init: zero h, load xs, Wv, bv ----
  for (int i = tid; i < NP * HROW; i += NTHR) {
    h1_s[i] = (_Float16)0.0f; h2_s[i] = (_Float16)0.0f;
  }
  if (tid < NP) wsum_s[tid] = 0.0f;
  if (tid < 2 * NH) ((float*)hsum2_s)[tid] = 0.0f;
  if (tid < NT * 16) {
    const int t = tid >> 4, i = tid & 15;
    float v = 0.0f;
    if (i < NIN) v = input_data[(b * NT + t) * NIN + i];
    else if (i == NIN) v = y_prev[b * NT + t];
    xs_all[t][i] = v;
  }
  for (int e = tid; e < NH * (NIN1 + NH); e += NTHR) {
    const int u = e / (NIN1 + NH), m = e % (NIN1 + NH);
    Wv_s[u * WVR + m] = Wv[e];
  }
  if (tid < NH) bv_s[tid] = bv[tid];
  __syncthreads();

  // ---- init pass 2: xg_all, lpx (need xs_all) ----
  #pragma unroll
  for (int j = 0; j < (NT * NP) / NTHR; ++j) {
    const int e = tid + j * NTHR;
    const int t = e >> 8, rr = e & 255;
    const int orow = (rr & 3) * NH + (rr >> 2);
    float a = b_ih[orow] + b_hh[orow];
    const float* wr = W_ih + orow * NIN1;
    #pragma unroll
    for (int i = 0; i < NIN1; ++i) a = fmaf(xs_all[t][i], wr[i], a);
    xg_all[e] = a;
  }
  if (tid < NT) {
    float xp = bp0;
    #pragma unroll
    for (int i = 0; i < NIN1; ++i) xp = fmaf(xs_all[tid][i], Wp[NH + i], xp);
    lpx_s[tid] = xp;
  }

  // W' A-fragments (2-way f16 split), loaded ONCE: r' = 32wq+ln31, orig row (r'&3)*64+(r'>>2)
  const int rp   = 32 * wq + ln31;
  const int orig = (rp & 3) * NH + (rp >> 2);
  f16x8 w1f[4], w2f[4];
  #pragma unroll
  for (int kt = 0; kt < 4; ++kt) {
    #pragma unroll
    for (int e = 0; e < 8; ++e) {
      float x = W_hh[orig * NH + kt * 16 + h5 * 8 + e];
      _Float16 a = (_Float16)x;
      w1f[kt][e] = a;
      w2f[kt][e] = (_Float16)(x - (float)a);
    }
  }
  float wf_r[4], wp_r[4];
  #pragma unroll
  for (int q = 0; q < 4; ++q) {
    const int kq = 8 * wq + 2 * q + h5;
    wf_r[q] = Wf[kq];
    wp_r[q] = Wp[kq];
  }

  // c state in registers: static cell ownership, never sorted
  float cA[2][4], cB[2][4];
  #pragma unroll
  for (int mi = 0; mi < 2; ++mi) {
    #pragma unroll
    for (int q = 0; q < 4; ++q) { cA[mi][q] = 0.0f; cB[mi][q] = 0.0f; }
  }

  // parallel finalize: std (4 thr/unit) + proj/lp init, for step tn
  auto finalize_init = [&](int tn) {
    if (tid < 4 * NH) {
      const int u = tid >> 2, s = tid & 3;
      float v = 0.0f;
      for (int m = s; m < NIN1 + NH; m += 4) {
        const float wv_ = Wv_s[u * WVR + m];
        const float x = (m < NIN1) ? xs_all[tn][m]
                                   : (hsum2_s[0][m - NIN1] + hsum2_s[1][m - NIN1]) * (1.0f / NP);
        v = fmaf(x, wv_, v);
      }
      v += __shfl_xor(v, 1, 64);
      v += __shfl_xor(v, 2, 64);
      if (s == 0) {
        v += bv_s[u];
        std_s[u] = fmaxf(v, 0.0f) + log1pf(expf(-fabsf(v)));   // softplus, libm exact
      }
    }
    if (tid < NP) {
      proj_s[tid] = bf0;
      lp_s[tid] = lpx_s[tn];
    }
  };

  __syncthreads();
  finalize_init(0);
  __syncthreads();

  for (int t = 0; t < NT; ++t) {
    // ================= phase 2a: MFMA + elementwise =================
    float std_r[4];
    #pragma unroll
    for (int q = 0; q < 4; ++q) std_r[q] = std_s[8 * wq + 2 * q + h5];

    const uint32_t fk0 = fk.a[t], fk1 = fk.b[t];
    float hs[4] = {0.0f, 0.0f, 0.0f, 0.0f};
    uint32_t sH1[2][4], sH2[2][4];   // exchanged row-halves staged for phase F
    const float* xgt = &xg_all[t * NP + 32 * wq + 4 * h5];

    #pragma unroll
    for (int mi = 0; mi < 2; ++mi) {
      const int pA = (2 * mh + mi) * 32 + ln31;

      // ---- tile A (rows pA) ----
      f32x16 acc;
      #pragma unroll
      for (int q = 0; q < 4; ++q) {
        const float4 v = *(const float4*)&xgt[8 * q];
        acc[4 * q + 0] = v.x; acc[4 * q + 1] = v.y;
        acc[4 * q + 2] = v.z; acc[4 * q + 3] = v.w;
      }
      #pragma unroll
      for (int kt = 0; kt < 4; ++kt) {
        const int off = kt * 16 + h5 * 8;
        const f16x8 b1 = ld8h(&h1_s[pA * HROW + off]);
        const f16x8 b2 = ld8h(&h2_s[pA * HROW + off]);
        acc = __builtin_amdgcn_mfma_f32_32x32x16_f16(w1f[kt], b1, acc, 0, 0, 0);
        acc = __builtin_amdgcn_mfma_f32_32x32x16_f16(w1f[kt], b2, acc, 0, 0, 0);
        acc = __builtin_amdgcn_mfma_f32_32x32x16_f16(w2f[kt], b1, acc, 0, 0, 0);
      }
      float hlA[4];
      #pragma unroll
      for (int q = 0; q < 4; ++q) {
        float si = fsigmoid(acc[4 * q + 0]);
        float sf = fsigmoid(acc[4 * q + 1]);
        float so = fsigmoid(acc[4 * q + 3]);
        float cn = sf * cA[mi][q] + si * ftanh(acc[4 * q + 2]);
        cA[mi][q] = cn;
        hlA[q] = so * ftanh(cn);
      }
      // ---- tile B (rows pA+128) ----
      #pragma unroll
      for (int q = 0; q < 4; ++q) {
        const float4 v = *(const float4*)&xgt[8 * q];
        acc[4 * q + 0] = v.x; acc[4 * q + 1] = v.y;
        acc[4 * q + 2] = v.z; acc[4 * q + 3] = v.w;
      }
      #pragma unroll
      for (int kt = 0; kt < 4; ++kt) {
        const int off = kt * 16 + h5 * 8;
        const f16x8 b1 = ld8h(&h1_s[(pA + 128) * HROW + off]);
        const f16x8 b2 = ld8h(&h2_s[(pA + 128) * HROW + off]);
        acc = __builtin_amdgcn_mfma_f32_32x32x16_f16(w1f[kt], b1, acc, 0, 0, 0);
        acc = __builtin_amdgcn_mfma_f32_32x32x16_f16(w1f[kt], b2, acc, 0, 0, 0);
        acc = __builtin_amdgcn_mfma_f32_32x32x16_f16(w2f[kt], b1, acc, 0, 0, 0);
      }
      float plA = 0.0f, lpA = 0.0f, plB = 0.0f, lpB = 0.0f;
      #pragma unroll
      for (int q = 0; q < 4; ++q) {
        float si = fsigmoid(acc[4 * q + 0]);
        float sf = fsigmoid(acc[4 * q + 1]);
        float so = fsigmoid(acc[4 * q + 3]);
        float cn = sf * cB[mi][q] + si * ftanh(acc[4 * q + 2]);
        cB[mi][q] = cn;
        float hlB = so * ftanh(cn);
        const int kq = 8 * wq + 2 * q + h5;
        // shared threefry: pair (idx, idx + 2^22) = slots (pA, pA+128)
        uint32_t x0 = ((uint32_t)pA << 15) | bsh | (uint32_t)kq;
        uint32_t x1 = x0 + (1u << 22);
        threefry2x32(fk0, fk1, x0, x1);
        float eA = normal_from_bits(x0);
        float eB = normal_from_bits(x1);
        float hrA = fmaf(eA, std_r[q], hlA[q]);
        float hrB = fmaf(eB, std_r[q], hlB);
        hs[q] += hrA + hrB;
        plA = fmaf(hrA, wf_r[q], plA); lpA = fmaf(hrA, wp_r[q], lpA);
        plB = fmaf(hrB, wf_r[q], plB); lpB = fmaf(hrB, wp_r[q], lpB);
        // immediate cross-lane exchange: assemble this thread's write row-half
        const uint32_t pkA = pack_split(hrA);
        const uint32_t pkB = pack_split(hrB);
        const uint32_t send = h5 ? pkA : pkB;
        const uint32_t got  = (uint32_t)__shfl_xor((int)send, 32, 64);
        const uint32_t ev = h5 ? got : pkA;   // k = 8wq+2q   (even)
        const uint32_t od = h5 ? pkB : got;   // k = 8wq+2q+1 (odd)
        sH1[mi][q] = (ev & 0xffffu) | (od << 16);
        sH2[mi][q] = (ev >> 16) | (od & 0xffff0000u);
      }
      plA += __shfl_xor(plA, 32, 64); lpA += __shfl_xor(lpA, 32, 64);
      plB += __shfl_xor(plB, 32, 64); lpB += __shfl_xor(lpB, 32, 64);
      if (lane < 32) {
        atomicAdd(&proj_s[pA], plA);
        atomicAdd(&lp_s[pA], lpA);
        atomicAdd(&proj_s[pA + 128], plB);
        atomicAdd(&lp_s[pA + 128], lpB);
      }
    }
    // hsum: butterfly over 32-lane group; (wq,mh,h5,q) -> hsum2_s[mh][k]
    #pragma unroll
    for (int q = 0; q < 4; ++q) {
      float s = hs[q];
      s += __shfl_xor(s, 1, 64); s += __shfl_xor(s, 2, 64); s += __shfl_xor(s, 4, 64);
      s += __shfl_xor(s, 8, 64); s += __shfl_xor(s, 16, 64);
      if (ln31 == q) hsum2_s[mh][8 * wq + 2 * q + h5] = s;
    }
    __syncthreads();   // b1: h reads + proj/lp atomics + hsum done

    // ================= phase R: split stable-rank (1024 quarter-jobs) ============
    {
      const int ph = tid & (NP - 1);
      const int qh = tid >> 8;          // 0..3
      const float pv = proj_s[ph];
      int rk = 0;
      const float4* c4 = (const float4*)proj_s;
      #pragma unroll 8
      for (int q4 = 16 * qh; q4 < 16 * qh + 16; ++q4) {
        float4 v = c4[q4];
        int qb = q4 * 4;
        rk += (v.x < pv || (v.x == pv && qb + 0 < ph)) ? 1 : 0;
        rk += (v.y < pv || (v.y == pv && qb + 1 < ph)) ? 1 : 0;
        rk += (v.z < pv || (v.z == pv && qb + 2 < ph)) ? 1 : 0;
        rk += (v.w < pv || (v.w == pv && qb + 3 < ph)) ? 1 : 0;
      }
      rankP_s[qh][ph] = rk;
    }
    __syncthreads();   // b2: rank partials ready

    // ================= phase F: scatter h at ranked rows + wsum + next init =====
    #pragma unroll
    for (int mi = 0; mi < 2; ++mi) {
      const int src = (2 * mh + mi) * 32 + ln31 + (h5 ? 128 : 0);
      const int tgt = rankP_s[0][src] + rankP_s[1][src] + rankP_s[2][src] + rankP_s[3][src];
      _Float16* d1 = &h1_s[tgt * HROW + 8 * wq];
      _Float16* d2 = &h2_s[tgt * HROW + 8 * wq];
      *(uint64_t*)(d1)     = (uint64_t)sH1[mi][0] | ((uint64_t)sH1[mi][1] << 32);
      *(uint64_t*)(d1 + 4) = (uint64_t)sH1[mi][2] | ((uint64_t)sH1[mi][3] << 32);
      *(uint64_t*)(d2)     = (uint64_t)sH2[mi][0] | ((uint64_t)sH2[mi][1] << 32);
      *(uint64_t*)(d2 + 4) = (uint64_t)sH2[mi][2] | ((uint64_t)sH2[mi][3] << 32);
    }
    if (tid < NP) {
      const int rank = rankP_s[0][tid] + rankP_s[1][tid] + rankP_s[2][tid] + rankP_s[3][tid];
      wsum_s[rank] += __expf(lp_s[tid]);   // ranks form a permutation -> race-free
    }
    finalize_init((t + 1 < NT) ? t + 1 : t);
    __syncthreads();   // b3 (loop end): h writes + next-step init visible
  }

  // ---- epilogue: y_pred[b] = mean_p(h_fin) @ Wf + bf ----
  if (tid < NH) {
    float hm = (hsum2_s[0][tid] + hsum2_s[1][tid]) * (1.0f / NP);
    float contrib = hm * Wf[tid];
    contrib += __shfl_xor(contrib, 32, 64);
    contrib += __shfl_xor(contrib, 16, 64);
    contrib += __shfl_xor(contrib, 8, 64);
    contrib += __shfl_xor(contrib, 4, 64);
    contrib += __shfl_xor(contrib, 2, 64);
    contrib += __shfl_xor(contrib, 1, 64);
    if (tid == 0) out[b] = contrib + bf0;
  }
  if (tid < NP) gw[(size_t)tid * NB + b] = wsum_s[tid];
}

// weights[i] = (1/256) * sum_{j<256} gw[(i>>1)*512 + (i&1)*256 + j]
__global__ __launch_bounds__(64, 1)
void pf_weights(const float* __restrict__ gw, float* __restrict__ out) {
  int i = blockIdx.x;
  int lane = threadIdx.x;
  const float* src = gw + ((size_t)(i >> 1)) * NB + (size_t)(i & 1) * NP;
  float4 v = ((const float4*)src)[lane];
  float s = (v.x + v.y) + (v.z + v.w);
  s += __shfl_xor(s, 32, 64);
  s += __shfl_xor(s, 16, 64);
  s += __shfl_xor(s, 8, 64);
  s += __shfl_xor(s, 4, 64);
  s += __shfl_xor(s, 2, 64);
  s += __shfl_xor(s, 1, 64);
  if (lane == 0) out[NB + i] = s * (1.0f / NP);
}

extern "C" void kernel_launch(void* const* d_in, const int* in_sizes, int n_in,
                              void* d_out, int out_size, void* d_ws, size_t ws_size,
                              hipStream_t stream) {
  (void)in_sizes; (void)n_in; (void)out_size; (void)ws_size;
  const float* input_data = (const float*)d_in[0];
  const float* y_prev     = (const float*)d_in[1];
  const float* Wv         = (const float*)d_in[2];
  const float* bv         = (const float*)d_in[3];
  const float* W_ih       = (const float*)d_in[4];
  const float* W_hh       = (const float*)d_in[5];
  const float* b_ih       = (const float*)d_in[6];
  const float* b_hh       = (const float*)d_in[7];
  const float* Wp         = (const float*)d_in[8];
  const float* bp         = (const float*)d_in[9];
  const float* Wf         = (const float*)d_in[10];
  const float* bf         = (const float*)d_in[11];
  float* out = (float*)d_out;
  float* gw  = (float*)d_ws;                           // [P][B] f32 = 512 KB

  FKeys fk;
  for (int t = 0; t < NT; ++t) {
    uint32_t x0 = 0u, x1 = (uint32_t)t;
    threefry2x32(0u, 1234u, x0, x1);
    fk.a[t] = x0; fk.b[t] = x1;
  }

  pf_main<<<dim3(NB), dim3(NTHR), 0, stream>>>(
      input_data, y_prev, Wv, bv, W_ih, W_hh, b_ih, b_hh, Wp, bp, Wf, bf,
      out, gw, fk);
  pf_weights<<<dim3(NB), dim3(64), 0, stream>>>(gw, out);
}

// Round 11
// 1551.141 us; speedup vs baseline: 1.6979x; 1.6979x over previous
//
#include <hip/hip_runtime.h>
#include <stdint.h>

#define NB 512   // batch
#define NT 32    // time steps
#define NIN 8    // input feats
#define NIN1 9   // + y_prev
#define NH 64    // hidden
#define NP 256   // particles
#define NTHR 512 // 8 waves: wave wq owns gate-rows r' in [32wq, 32wq+32)
#define HROW 68  // f16 row stride: 136 B = 34 dwords -> 2-way bank alias (free)

typedef __attribute__((ext_vector_type(8))) _Float16 f16x8;
typedef __attribute__((ext_vector_type(16))) float f32x16;

struct FKeys { uint32_t a[NT]; uint32_t b[NT]; };

// ---------------- Threefry-2x32-20 (exact JAX semantics) ----------------
__host__ __device__ __forceinline__ void tfr(uint32_t& x0, uint32_t& x1, int r) {
  x0 += x1; x1 = (x1 << r) | (x1 >> (32 - r)); x1 ^= x0;
}

__host__ __device__ __forceinline__ void threefry2x32(uint32_t k0, uint32_t k1,
                                                      uint32_t& x0, uint32_t& x1) {
  uint32_t k2 = k0 ^ k1 ^ 0x1BD11BDAu;
  x0 += k0; x1 += k1;
  tfr(x0,x1,13); tfr(x0,x1,15); tfr(x0,x1,26); tfr(x0,x1,6);
  x0 += k1; x1 += k2 + 1u;
  tfr(x0,x1,17); tfr(x0,x1,29); tfr(x0,x1,16); tfr(x0,x1,24);
  x0 += k2; x1 += k0 + 2u;
  tfr(x0,x1,13); tfr(x0,x1,15); tfr(x0,x1,26); tfr(x0,x1,6);
  x0 += k0; x1 += k1 + 3u;
  tfr(x0,x1,17); tfr(x0,x1,29); tfr(x0,x1,16); tfr(x0,x1,24);
  x0 += k1; x1 += k2 + 4u;
  tfr(x0,x1,13); tfr(x0,x1,15); tfr(x0,x1,26); tfr(x0,x1,6);
  x0 += k2; x1 += k0 + 5u;
}

// bits -> uniform -> sqrt(2)*erfinv  (XLA f32 path)
// log1p(-u*u) replaced by __logf(fmaf(-u,u,1)) : fma gives 1-u^2 in one rounding
// (exact product, no cancellation), v_log_f32 ~1 ulp -> eps error ~1e-6 (same
// class as the f16-split GEMM error, which passes at absmax 0.5).
__device__ __forceinline__ float normal_from_bits(uint32_t bits) {
  float f = __uint_as_float((bits >> 9) | 0x3f800000u) - 1.0f;
  const float lo = -0.99999994f;
  float u = fmaxf(lo, fmaf(f, 2.0f, lo));
  float w = -__logf(fmaf(-u, u, 1.0f));
  float p;
  if (w < 5.0f) {
    w -= 2.5f;
    p = 2.81022636e-08f;
    p = fmaf(p, w, 3.43273939e-07f);
    p = fmaf(p, w, -3.5233877e-06f);
    p = fmaf(p, w, -4.39150654e-06f);
    p = fmaf(p, w, 0.00021858087f);
    p = fmaf(p, w, -0.00125372503f);
    p = fmaf(p, w, -0.00417768164f);
    p = fmaf(p, w, 0.246640727f);
    p = fmaf(p, w, 1.50140941f);
  } else {
    w = sqrtf(w) - 3.0f;
    p = -0.000200214257f;
    p = fmaf(p, w, 0.000100950558f);
    p = fmaf(p, w, 0.00134934322f);
    p = fmaf(p, w, -0.00367342844f);
    p = fmaf(p, w, 0.00573950773f);
    p = fmaf(p, w, -0.0076224613f);
    p = fmaf(p, w, 0.00943887047f);
    p = fmaf(p, w, 1.00167406f);
    p = fmaf(p, w, 2.83297682f);
  }
  return 1.41421356f * (p * u);
}

__device__ __forceinline__ float frcp(float x) { return __builtin_amdgcn_rcpf(x); }
__device__ __forceinline__ float fsigmoid(float x) { return frcp(1.0f + __expf(-x)); }
__device__ __forceinline__ float ftanh(float x) { return 1.0f - 2.0f * frcp(1.0f + __expf(2.0f * x)); }

// f32 -> packed (f16 hi | f16 residual) : h = h1 + h2 with ~22-bit combined mantissa
__device__ __forceinline__ uint32_t pack_split(float x) {
  _Float16 a = (_Float16)x;
  _Float16 r = (_Float16)(x - (float)a);
  union { _Float16 h; uint16_t u; } ua, ur;
  ua.h = a; ur.h = r;
  return (uint32_t)ua.u | ((uint32_t)ur.u << 16);
}

// 8B-aligned LDS f16x8 load (two ds_read_b64, 2-way alias at HROW=68)
__device__ __forceinline__ f16x8 ld8h(const _Float16* p) {
  union { f16x8 v; uint64_t q[2]; } u;
  u.q[0] = *(const uint64_t*)(p);
  u.q[1] = *(const uint64_t*)(p + 4);
  return u.v;
}

// ---------------- main kernel: one block (512 thr) per batch elem ----------------
// Gates GEMM per step: D[r'][p] = sum_j W'[r'][j] h[p][j], r' = 4k+gate.
// A = W' (2-way f16 split in registers, loaded once); B = h (f16 splits in LDS,
// physical rows == sorted slots; reads sequential -> conflict-free).
// Wave wq: lane (ln31,h5) owns cells (p = mm*32+ln31 [+128], k = 8wq+2q+h5), mm=0..3.
// New h is scatter-written directly at the ranked row in phase F.
// launch_bounds(512,1): arch-VGPR cap ~256 so the ~200-reg live set stays in
// VGPRs (no accvgpr shuffle, no scratch). Occupancy is 8 waves/CU either way.
__global__ __launch_bounds__(NTHR, 1)
void pf_main(const float* __restrict__ input_data, const float* __restrict__ y_prev,
             const float* __restrict__ Wv, const float* __restrict__ bv,
             const float* __restrict__ W_ih, const float* __restrict__ W_hh,
             const float* __restrict__ b_ih, const float* __restrict__ b_hh,
             const float* __restrict__ Wp, const float* __restrict__ bp,
             const float* __restrict__ Wf, const float* __restrict__ bf,
             float* __restrict__ out, float* __restrict__ gw,
             FKeys fk)
{
  __shared__ __align__(16) _Float16 h1_s[NP * HROW];  // 34.8 KB
  __shared__ __align__(16) _Float16 h2_s[NP * HROW];  // 34.8 KB
  __shared__ __align__(16) float xg_s[NP];
  __shared__ __align__(16) float proj_s[NP];
  __shared__ float lp_s[NP];
  __shared__ float wsum_s[NP];
  __shared__ int   rankP_s[2 * NP];
  __shared__ float hsum_s[NH];
  __shared__ float std_s[NH];
  __shared__ float xs_s[16];

  const int tid  = threadIdx.x;
  const int b    = blockIdx.x;
  const int lane = tid & 63;
  const int wq   = tid >> 6;          // wave 0..7: gate-row group
  const int ln31 = lane & 31;
  const int h5   = lane >> 5;

  // ---- one-time init ----
  for (int i = tid; i < NP * HROW; i += NTHR) {
    h1_s[i] = (_Float16)0.0f; h2_s[i] = (_Float16)0.0f;
  }
  if (tid < NP) wsum_s[tid] = 0.0f;
  if (tid < NH) hsum_s[tid] = 0.0f;

  const float bf0 = bf[0];
  const float bp0 = bp[0];
  const uint32_t bsh = (uint32_t)b << 6;

  // W' A-fragments (2-way f16 split), loaded ONCE: r' = 32wq+ln31, orig row (r'&3)*64+(r'>>2)
  const int rp   = 32 * wq + ln31;
  const int orig = (rp & 3) * NH + (rp >> 2);
  f16x8 w1f[4], w2f[4];
  #pragma unroll
  for (int kt = 0; kt < 4; ++kt) {
    #pragma unroll
    for (int e = 0; e < 8; ++e) {
      float x = W_hh[orig * NH + kt * 16 + h5 * 8 + e];
      _Float16 a = (_Float16)x;
      w1f[kt][e] = a;
      w2f[kt][e] = (_Float16)(x - (float)a);
    }
  }

  float wf_r[4], wp_r[4];
  #pragma unroll
  for (int q = 0; q < 4; ++q) {
    const int kq = 8 * wq + 2 * q + h5;
    wf_r[q] = Wf[kq];
    wp_r[q] = Wp[kq];
  }

  // c state in registers: static cell ownership, never sorted
  float cA[4][4], cB[4][4];
  #pragma unroll
  for (int mi = 0; mi < 4; ++mi) {
    #pragma unroll
    for (int q = 0; q < 4; ++q) { cA[mi][q] = 0.0f; cB[mi][q] = 0.0f; }
  }

  // finalize block: std + xg + proj/lp init for the upcoming step (reads xs_s, hsum_s)
  auto finalize_init = [&]() {
    if (tid < NH) {
      float v = bv[tid];
      const float* wvr = Wv + tid * (NIN1 + NH);
      #pragma unroll
      for (int i = 0; i < NIN1; ++i) v = fmaf(xs_s[i], wvr[i], v);
      #pragma unroll
      for (int k = 0; k < NH; ++k)
        v = fmaf(hsum_s[k] * (1.0f / NP), wvr[NIN1 + k], v);
      std_s[tid] = fmaxf(v, 0.0f) + log1pf(expf(-fabsf(v)));   // softplus, libm exact
    }
    if (tid < NP) {
      const int orow = (tid & 3) * NH + (tid >> 2);
      float a = b_ih[orow] + b_hh[orow];
      const float* wr = W_ih + orow * NIN1;
      #pragma unroll
      for (int i = 0; i < NIN1; ++i) a = fmaf(xs_s[i], wr[i], a);
      xg_s[tid] = a;
      proj_s[tid] = bf0;
      float xp = bp0;
      #pragma unroll
      for (int i = 0; i < NIN1; ++i) xp = fmaf(xs_s[i], Wp[NH + i], xp);
      lp_s[tid] = xp;
    }
  };

  if (tid < NIN) xs_s[tid] = input_data[(b * NT + 0) * NIN + tid];
  if (tid == NIN) xs_s[NIN] = y_prev[b * NT + 0];
  __syncthreads();
  finalize_init();
  __syncthreads();

  for (int t = 0; t < NT; ++t) {
    // ================= phase 2a: MFMA + elementwise (+ xs_{t+1} prefetch) ========
    // xs_s is dead during this phase (consumed by finalize at end of t-1)
    if (tid < 16 && t + 1 < NT) {
      if (tid < NIN) xs_s[tid] = input_data[(b * NT + t + 1) * NIN + tid];
      if (tid == NIN) xs_s[NIN] = y_prev[b * NT + t + 1];
    }

    float xgr[16];
    #pragma unroll
    for (int q = 0; q < 4; ++q) {
      const float4 v = *(const float4*)&xg_s[32 * wq + 8 * q + 4 * h5];
      xgr[4 * q + 0] = v.x; xgr[4 * q + 1] = v.y;
      xgr[4 * q + 2] = v.z; xgr[4 * q + 3] = v.w;
    }
    float std_r[4];
    #pragma unroll
    for (int q = 0; q < 4; ++q) std_r[q] = std_s[8 * wq + 2 * q + h5];

    const uint32_t fk0 = fk.a[t], fk1 = fk.b[t];
    float hs[4] = {0.0f, 0.0f, 0.0f, 0.0f};
    uint32_t sH1[4][4], sH2[4][4];   // exchanged row-halves staged for phase F

    #pragma unroll
    for (int mi = 0; mi < 4; ++mi) {
      const int pA = mi * 32 + ln31;

      // ---- tile A (rows pA) ----
      f32x16 acc;
      #pragma unroll
      for (int r = 0; r < 16; ++r) acc[r] = xgr[r];
      #pragma unroll
      for (int kt = 0; kt < 4; ++kt) {
        const int off = kt * 16 + h5 * 8;
        const f16x8 b1 = ld8h(&h1_s[pA * HROW + off]);
        const f16x8 b2 = ld8h(&h2_s[pA * HROW + off]);
        acc = __builtin_amdgcn_mfma_f32_32x32x16_f16(w1f[kt], b1, acc, 0, 0, 0);
        acc = __builtin_amdgcn_mfma_f32_32x32x16_f16(w1f[kt], b2, acc, 0, 0, 0);
        acc = __builtin_amdgcn_mfma_f32_32x32x16_f16(w2f[kt], b1, acc, 0, 0, 0);
      }
      float hlA[4];
      #pragma unroll
      for (int q = 0; q < 4; ++q) {
        float si = fsigmoid(acc[4 * q + 0]);
        float sf = fsigmoid(acc[4 * q + 1]);
        float so = fsigmoid(acc[4 * q + 3]);
        float cn = sf * cA[mi][q] + si * ftanh(acc[4 * q + 2]);
        cA[mi][q] = cn;
        hlA[q] = so * ftanh(cn);
      }
      // ---- tile B (rows pA+128) ----
      #pragma unroll
      for (int r = 0; r < 16; ++r) acc[r] = xgr[r];
      #pragma unroll
      for (int kt = 0; kt < 4; ++kt) {
        const int off = kt * 16 + h5 * 8;
        const f16x8 b1 = ld8h(&h1_s[(pA + 128) * HROW + off]);
        const f16x8 b2 = ld8h(&h2_s[(pA + 128) * HROW + off]);
        acc = __builtin_amdgcn_mfma_f32_32x32x16_f16(w1f[kt], b1, acc, 0, 0, 0);
        acc = __builtin_amdgcn_mfma_f32_32x32x16_f16(w1f[kt], b2, acc, 0, 0, 0);
        acc = __builtin_amdgcn_mfma_f32_32x32x16_f16(w2f[kt], b1, acc, 0, 0, 0);
      }
      float plA = 0.0f, lpA = 0.0f, plB = 0.0f, lpB = 0.0f;
      #pragma unroll
      for (int q = 0; q < 4; ++q) {
        float si = fsigmoid(acc[4 * q + 0]);
        float sf = fsigmoid(acc[4 * q + 1]);
        float so = fsigmoid(acc[4 * q + 3]);
        float cn = sf * cB[mi][q] + si * ftanh(acc[4 * q + 2]);
        cB[mi][q] = cn;
        float hlB = so * ftanh(cn);
        const int kq = 8 * wq + 2 * q + h5;
        // shared threefry: pair (idx, idx + 2^22) = slots (pA, pA+128)
        uint32_t x0 = ((uint32_t)pA << 15) | bsh | (uint32_t)kq;
        uint32_t x1 = x0 + (1u << 22);
        threefry2x32(fk0, fk1, x0, x1);
        float eA = normal_from_bits(x0);
        float eB = normal_from_bits(x1);
        float hrA = fmaf(eA, std_r[q], hlA[q]);
        float hrB = fmaf(eB, std_r[q], hlB);
        hs[q] += hrA + hrB;
        plA = fmaf(hrA, wf_r[q], plA); lpA = fmaf(hrA, wp_r[q], lpA);
        plB = fmaf(hrB, wf_r[q], plB); lpB = fmaf(hrB, wp_r[q], lpB);
        // immediate cross-lane exchange: assemble this thread's write row-half
        const uint32_t pkA = pack_split(hrA);
        const uint32_t pkB = pack_split(hrB);
        const uint32_t send = h5 ? pkA : pkB;
        const uint32_t got  = (uint32_t)__shfl_xor((int)send, 32, 64);
        const uint32_t ev = h5 ? got : pkA;   // k = 8wq+2q   (even)
        const uint32_t od = h5 ? pkB : got;   // k = 8wq+2q+1 (odd)
        sH1[mi][q] = (ev & 0xffffu) | (od << 16);
        sH2[mi][q] = (ev >> 16) | (od & 0xffff0000u);
      }
      plA += __shfl_xor(plA, 32, 64); lpA += __shfl_xor(lpA, 32, 64);
      plB += __shfl_xor(plB, 32, 64); lpB += __shfl_xor(lpB, 32, 64);
      if (lane < 32) {
        atomicAdd(&proj_s[pA], plA);
        atomicAdd(&lp_s[pA], lpA);
        atomicAdd(&proj_s[pA + 128], plB);
        atomicAdd(&lp_s[pA + 128], lpB);
      }
    }
    // hsum: butterfly over 32-lane group; k = 8wq+2q+h5 (covers all 64 k, all 256 p)
    #pragma unroll
    for (int q = 0; q < 4; ++q) {
      float s = hs[q];
      s += __shfl_xor(s, 1, 64); s += __shfl_xor(s, 2, 64); s += __shfl_xor(s, 4, 64);
      s += __shfl_xor(s, 8, 64); s += __shfl_xor(s, 16, 64);
      if (ln31 == q) hsum_s[8 * wq + 2 * q + h5] = s;
    }
    __syncthreads();   // b1: h reads + proj/lp atomics + xs_next done

    // ================= phase R: split stable-rank (512 half-jobs) =================
    {
      const int ph = tid & (NP - 1);
      const int hh = tid >> 8;
      const float pv = proj_s[ph];
      int rk = 0;
      const float4* c4 = (const float4*)proj_s;
      #pragma unroll 8
      for (int q4 = 32 * hh; q4 < 32 * hh + 32; ++q4) {
        float4 v = c4[q4];
        int qb = q4 * 4;
        rk += (v.x < pv || (v.x == pv && qb + 0 < ph)) ? 1 : 0;
        rk += (v.y < pv || (v.y == pv && qb + 1 < ph)) ? 1 : 0;
        rk += (v.z < pv || (v.z == pv && qb + 2 < ph)) ? 1 : 0;
        rk += (v.w < pv || (v.w == pv && qb + 3 < ph)) ? 1 : 0;
      }
      rankP_s[hh * NP + ph] = rk;
    }
    __syncthreads();   // b2: rank partials ready

    // ================= phase F: scatter h at ranked rows + wsum + next init =====
    #pragma unroll
    for (int mi = 0; mi < 4; ++mi) {
      const int src = mi * 32 + ln31 + (h5 ? 128 : 0);
      const int tgt = rankP_s[src] + rankP_s[NP + src];
      _Float16* d1 = &h1_s[tgt * HROW + 8 * wq];
      _Float16* d2 = &h2_s[tgt * HROW + 8 * wq];
      *(uint64_t*)(d1)     = (uint64_t)sH1[mi][0] | ((uint64_t)sH1[mi][1] << 32);
      *(uint64_t*)(d1 + 4) = (uint64_t)sH1[mi][2] | ((uint64_t)sH1[mi][3] << 32);
      *(uint64_t*)(d2)     = (uint64_t)sH2[mi][0] | ((uint64_t)sH2[mi][1] << 32);
      *(uint64_t*)(d2 + 4) = (uint64_t)sH2[mi][2] | ((uint64_t)sH2[mi][3] << 32);
    }
    if (tid < NP) {
      const int rank = rankP_s[tid] + rankP_s[NP + tid];
      wsum_s[rank] += __expf(lp_s[tid]);   // ranks form a permutation -> race-free
    }
    finalize_init();
    __syncthreads();   // b3 (loop end): h writes + next-step init visible
  }

  // ---- epilogue: y_pred[b] = mean_p(h_fin) @ Wf + bf ----
  if (tid < NH) {
    float hm = hsum_s[tid] * (1.0f / NP);
    float contrib = hm * Wf[tid];
    contrib += __shfl_xor(contrib, 32, 64);
    contrib += __shfl_xor(contrib, 16, 64);
    contrib += __shfl_xor(contrib, 8, 64);
    contrib += __shfl_xor(contrib, 4, 64);
    contrib += __shfl_xor(contrib, 2, 64);
    contrib += __shfl_xor(contrib, 1, 64);
    if (tid == 0) out[b] = contrib + bf0;
  }
  if (tid < NP) gw[(size_t)tid * NB + b] = wsum_s[tid];
}

// weights[i] = (1/256) * sum_{j<256} gw[(i>>1)*512 + (i&1)*256 + j]
__global__ __launch_bounds__(64, 1)
void pf_weights(const float* __restrict__ gw, float* __restrict__ out) {
  int i = blockIdx.x;
  int lane = threadIdx.x;
  const float* src = gw + ((size_t)(i >> 1)) * NB + (size_t)(i & 1) * NP;
  float4 v = ((const float4*)src)[lane];
  float s = (v.x + v.y) + (v.z + v.w);
  s += __shfl_xor(s, 32, 64);
  s += __shfl_xor(s, 16, 64);
  s += __shfl_xor(s, 8, 64);
  s += __shfl_xor(s, 4, 64);
  s += __shfl_xor(s, 2, 64);
  s += __shfl_xor(s, 1, 64);
  if (lane == 0) out[NB + i] = s * (1.0f / NP);
}

extern "C" void kernel_launch(void* const* d_in, const int* in_sizes, int n_in,
                              void* d_out, int out_size, void* d_ws, size_t ws_size,
                              hipStream_t stream) {
  (void)in_sizes; (void)n_in; (void)out_size; (void)ws_size;
  const float* input_data = (const float*)d_in[0];
  const float* y_prev     = (const float*)d_in[1];
  const float* Wv         = (const float*)d_in[2];
  const float* bv         = (const float*)d_in[3];
  const float* W_ih       = (const float*)d_in[4];
  const float* W_hh       = (const float*)d_in[5];
  const float* b_ih       = (const float*)d_in[6];
  const float* b_hh       = (const float*)d_in[7];
  const float* Wp         = (const float*)d_in[8];
  const float* bp         = (const float*)d_in[9];
  const float* Wf         = (const float*)d_in[10];
  const float* bf         = (const float*)d_in[11];
  float* out = (float*)d_out;
  float* gw  = (float*)d_ws;                           // [P][B] f32 = 512 KB

  FKeys fk;
  for (int t = 0; t < NT; ++t) {
    uint32_t x0 = 0u, x1 = (uint32_t)t;
    threefry2x32(0u, 1234u, x0, x1);
    fk.a[t] = x0; fk.b[t] = x1;
  }

  pf_main<<<dim3(NB), dim3(NTHR), 0, stream>>>(
      input_data, y_prev, Wv, bv, W_ih, W_hh, b_ih, b_hh, Wp, bp, Wf, bf,
      out, gw, fk);
  pf_weights<<<dim3(NB), dim3(64), 0, stream>>>(gw, out);
}